// Round 1
// baseline (409.270 us; speedup 1.0000x reference)
//
#include <hip/hip_runtime.h>

typedef __attribute__((ext_vector_type(8))) short short8;
typedef __attribute__((ext_vector_type(4))) short short4v;
typedef __attribute__((ext_vector_type(4))) float f32x4;

#define AS1 __attribute__((address_space(1)))
#define AS3 __attribute__((address_space(3)))

__device__ __forceinline__ void gld16(const void* g, void* l) {
  __builtin_amdgcn_global_load_lds((const AS1 void*)g, (AS3 void*)l, 16, 0, 0);
}

__device__ __forceinline__ short f2bf(float f) {
  unsigned u = __builtin_bit_cast(unsigned, f);
  unsigned r = (u + 0x7fffu + ((u >> 16) & 1u)) >> 16;
  return (short)r;
}

#define MFMA(a, b, c) __builtin_amdgcn_mfma_f32_16x16x32_bf16((a), (b), (c), 0, 0, 0)

// ---------------------------------------------------------------- cast f32->bf16
__global__ void cast_f32_bf16(const float* __restrict__ in, short* __restrict__ out, int n4) {
  int i = blockIdx.x * 256 + threadIdx.x;
  if (i >= n4) return;
  f32x4 v = ((const f32x4*)in)[i];
  short4v o;
  o[0] = f2bf(v[0]); o[1] = f2bf(v[1]); o[2] = f2bf(v[2]); o[3] = f2bf(v[3]);
  ((short4v*)out)[i] = o;
}

// ---------------------------------------------------------------- GEMM: C = A(MxK, lda) @ B(NxK,768)^T + bias
// 128x128 tile, BK=32, 4 waves (each 64x64), global_load_lds staging.
template <bool OUT_BF16>
__global__ __launch_bounds__(256) void gemm_bt(const short* __restrict__ A, int lda,
                                               const short* __restrict__ B,
                                               const float* __restrict__ bias,
                                               void* __restrict__ Cv, int K) {
  __shared__ alignas(16) short As[128 * 32];
  __shared__ alignas(16) short Bs[128 * 32];
  const int tid = threadIdx.x, wave = tid >> 6, lane = tid & 63;
  const int bm = blockIdx.x * 128, bn = blockIdx.y * 128;
  const int wr = (wave >> 1) * 64, wc = (wave & 1) * 64;
  const int l15 = lane & 15, g = lane >> 4;
  const int srow = lane >> 2;          // row within 16-row chunk
  const int skoff = (lane & 3) * 8;    // k element offset of this lane's 16B

  f32x4 zero = {0.f, 0.f, 0.f, 0.f};
  f32x4 acc[4][4];
#pragma unroll
  for (int m = 0; m < 4; ++m)
#pragma unroll
    for (int n = 0; n < 4; ++n) acc[m][n] = zero;

  for (int kt = 0; kt < K; kt += 32) {
#pragma unroll
    for (int c = 0; c < 2; ++c) {
      int chunk = wave * 2 + c;
      int r = chunk * 16 + srow;
      gld16(A + (size_t)(bm + r) * lda + kt + skoff, (char*)As + chunk * 1024);
      gld16(B + (size_t)(bn + r) * 768 + kt + skoff, (char*)Bs + chunk * 1024);
    }
    __syncthreads();
    short8 af[4], bfr[4];
#pragma unroll
    for (int m = 0; m < 4; ++m)
      af[m] = *(const short8*)((const char*)As + (wr + 16 * m + l15) * 64 + g * 16);
#pragma unroll
    for (int n = 0; n < 4; ++n)
      bfr[n] = *(const short8*)((const char*)Bs + (wc + 16 * n + l15) * 64 + g * 16);
#pragma unroll
    for (int m = 0; m < 4; ++m)
#pragma unroll
      for (int n = 0; n < 4; ++n) acc[m][n] = MFMA(af[m], bfr[n], acc[m][n]);
    __syncthreads();
  }

#pragma unroll
  for (int m = 0; m < 4; ++m)
#pragma unroll
    for (int n = 0; n < 4; ++n) {
      int col = bn + wc + 16 * n + l15;
      float bv = bias[col];
#pragma unroll
      for (int r = 0; r < 4; ++r) {
        int row = bm + wr + 16 * m + g * 4 + r;
        float v = acc[m][n][r] + bv;
        if (OUT_BF16)
          ((short*)Cv)[(size_t)row * 768 + col] = f2bf(v);
        else
          ((float*)Cv)[(size_t)row * 768 + col] = v;
      }
    }
}

// ---------------------------------------------------------------- attention
// block = (b,h, 64 q-rows), 4 waves x 16 q-rows. 512 dilated keys.
// K staged swizzled ((key&7)<<4); V staged swizzled (((key>>3)&3)<<5).
__global__ __launch_bounds__(256) void attn_kernel(const short* __restrict__ qb,
                                                   const short* __restrict__ kb,
                                                   const short* __restrict__ vb,
                                                   short* __restrict__ ctxb) {
  __shared__ alignas(16) char kv[32768];     // 256 keys x 64 bf16
  __shared__ alignas(16) char plds[4096];    // 4 waves x (16x32 bf16)
  const int tid = threadIdx.x, wave = tid >> 6, lane = tid & 63;
  const int b = blockIdx.y / 12, h = blockIdx.y % 12;
  const int qbase = blockIdx.x * 64;
  const int l15 = lane & 15, g = lane >> 4;

  // Q fragments: 16 rows x 64 k, two K=32 steps
  const short* qrow = qb + (size_t)(b * 4096 + qbase + wave * 16 + l15) * 768 + h * 64 + g * 8;
  short8 qa0 = *(const short8*)(qrow);
  short8 qa1 = *(const short8*)(qrow + 32);

  float s_[128];  // 32 tiles x 4 rows (f32 scores, this lane's column)
  f32x4 zero = {0.f, 0.f, 0.f, 0.f};

  // ---- scores: two halves of 256 keys
#pragma unroll
  for (int hh = 0; hh < 2; ++hh) {
#pragma unroll
    for (int c = 0; c < 8; ++c) {
      int chunk = wave * 8 + c;
      int key = chunk * 8 + (lane >> 3);
      int sb = ((lane & 7) * 16) ^ ((key & 7) << 4);
      gld16(kb + (size_t)(b * 512 + hh * 256 + key) * 768 + h * 64 + (sb >> 1),
            kv + chunk * 1024);
    }
    __syncthreads();
#pragma unroll
    for (int t = 0; t < 16; ++t) {
      int base = (t * 16 + l15) * 128;
      int swz = (lane & 7) << 4;
      short8 k0 = *(const short8*)(kv + ((base + g * 16) ^ swz));
      short8 k1 = *(const short8*)(kv + ((base + 64 + g * 16) ^ swz));
      f32x4 a = MFMA(qa0, k0, zero);
      a = MFMA(qa1, k1, a);
#pragma unroll
      for (int r = 0; r < 4; ++r) s_[(hh * 16 + t) * 4 + r] = a[r] * 0.125f;
    }
    __syncthreads();
  }

  // ---- softmax (exact, two-pass; rows spread over 16-lane groups)
  float mrow[4] = {-1e30f, -1e30f, -1e30f, -1e30f};
#pragma unroll
  for (int t = 0; t < 32; ++t)
#pragma unroll
    for (int r = 0; r < 4; ++r) mrow[r] = fmaxf(mrow[r], s_[t * 4 + r]);
#pragma unroll
  for (int r = 0; r < 4; ++r) {
    mrow[r] = fmaxf(mrow[r], __shfl_xor(mrow[r], 1, 64));
    mrow[r] = fmaxf(mrow[r], __shfl_xor(mrow[r], 2, 64));
    mrow[r] = fmaxf(mrow[r], __shfl_xor(mrow[r], 4, 64));
    mrow[r] = fmaxf(mrow[r], __shfl_xor(mrow[r], 8, 64));
  }
  float rsum[4] = {0.f, 0.f, 0.f, 0.f};
#pragma unroll
  for (int t = 0; t < 32; ++t)
#pragma unroll
    for (int r = 0; r < 4; ++r) {
      float p = expf(s_[t * 4 + r] - mrow[r]);
      s_[t * 4 + r] = p;
      rsum[r] += p;
    }
#pragma unroll
  for (int r = 0; r < 4; ++r) {
    rsum[r] += __shfl_xor(rsum[r], 1, 64);
    rsum[r] += __shfl_xor(rsum[r], 2, 64);
    rsum[r] += __shfl_xor(rsum[r], 4, 64);
    rsum[r] += __shfl_xor(rsum[r], 8, 64);
  }
  float rinv[4];
#pragma unroll
  for (int r = 0; r < 4; ++r) rinv[r] = 1.0f / rsum[r];

  // ---- PV: two halves of 256 keys
  f32x4 ctx[4];
#pragma unroll
  for (int n = 0; n < 4; ++n) ctx[n] = zero;
  char* pw = plds + wave * 1024;

#pragma unroll
  for (int vv = 0; vv < 2; ++vv) {
#pragma unroll
    for (int c = 0; c < 8; ++c) {
      int chunk = wave * 8 + c;
      int key = chunk * 8 + (lane >> 3);
      int sb = ((lane & 7) * 16) ^ (((key >> 3) & 3) << 5);
      gld16(vb + (size_t)(b * 512 + vv * 256 + key) * 768 + h * 64 + (sb >> 1),
            kv + chunk * 1024);
    }
    __syncthreads();
#pragma unroll
    for (int ks = 0; ks < 8; ++ks) {
      // transpose this wave's P chunk (16 rows x 32 keys) through LDS
#pragma unroll
      for (int tt = 0; tt < 2; ++tt)
#pragma unroll
        for (int r = 0; r < 4; ++r) {
          int row = g * 4 + r;
          int byte = ((row * 64 + (tt * 16 + l15) * 2)) ^ ((row & 7) << 4);
          *(short*)(pw + byte) = f2bf(s_[(vv * 16 + ks * 2 + tt) * 4 + r]);
        }
      short8 pa = *(const short8*)(pw + ((l15 * 64 + g * 16) ^ ((lane & 7) << 4)));
#pragma unroll
      for (int n = 0; n < 4; ++n) {
        int hd2 = (16 * n + l15) * 2;
        int swz = ((ks * 4 + g) & 3) << 5;
        short8 vf;
#pragma unroll
        for (int i = 0; i < 8; ++i)
          vf[i] = *(const short*)(kv + (((ks * 32 + 8 * g + i) * 128 + hd2) ^ swz));
        ctx[n] = MFMA(pa, vf, ctx[n]);
      }
    }
    __syncthreads();
  }

  // ---- write ctx (bf16) in (B,S,D) layout
  size_t rowbase = (size_t)(b * 4096 + qbase + wave * 16);
#pragma unroll
  for (int n = 0; n < 4; ++n)
#pragma unroll
    for (int r = 0; r < 4; ++r) {
      int row = g * 4 + r;
      float v = ctx[n][r] * rinv[r];
      ctxb[(rowbase + row) * 768 + h * 64 + 16 * n + l15] = f2bf(v);
    }
}

// ---------------------------------------------------------------- launch
extern "C" void kernel_launch(void* const* d_in, const int* in_sizes, int n_in,
                              void* d_out, int out_size, void* d_ws, size_t ws_size,
                              hipStream_t stream) {
  const float* x  = (const float*)d_in[0];
  const float* Wq = (const float*)d_in[1];
  const float* bq = (const float*)d_in[2];
  const float* Wk = (const float*)d_in[3];
  const float* bk = (const float*)d_in[4];
  const float* Wv = (const float*)d_in[5];
  const float* bv = (const float*)d_in[6];
  const float* Wo = (const float*)d_in[7];
  const float* bo = (const float*)d_in[8];

  char* ws = (char*)d_ws;
  const size_t XB_OFF = 0;                       // 16384x768 bf16 (reused as ctx)
  const size_t WQ_OFF = 25165824;
  const size_t WK_OFF = WQ_OFF + 1179648;
  const size_t WV_OFF = WK_OFF + 1179648;
  const size_t WO_OFF = WV_OFF + 1179648;
  const size_t Q_OFF  = WO_OFF + 1179648;        // 16384x768 bf16
  const size_t K_OFF  = Q_OFF + 25165824;        // 2048x768 bf16
  const size_t V_OFF  = K_OFF + 3145728;         // 2048x768 bf16

  short* xb   = (short*)(ws + XB_OFF);
  short* ctxb = xb;  // xb dead after V-projection; reuse for ctx
  short* wqb  = (short*)(ws + WQ_OFF);
  short* wkb  = (short*)(ws + WK_OFF);
  short* wvb  = (short*)(ws + WV_OFF);
  short* wob  = (short*)(ws + WO_OFF);
  short* qbf  = (short*)(ws + Q_OFF);
  short* kbf  = (short*)(ws + K_OFF);
  short* vbf  = (short*)(ws + V_OFF);

  cast_f32_bf16<<<12288, 256, 0, stream>>>(x, xb, 3145728);
  cast_f32_bf16<<<576, 256, 0, stream>>>(Wq, wqb, 147456);
  cast_f32_bf16<<<576, 256, 0, stream>>>(Wk, wkb, 147456);
  cast_f32_bf16<<<576, 256, 0, stream>>>(Wv, wvb, 147456);
  cast_f32_bf16<<<576, 256, 0, stream>>>(Wo, wob, 147456);

  // Q projection: all 16384 rows
  gemm_bt<true><<<dim3(128, 6), 256, 0, stream>>>(xb, 768, wqb, bq, qbf, 768);
  // K/V projections: dilated rows only (row m -> x row stride 8*768 = 6144)
  gemm_bt<true><<<dim3(16, 6), 256, 0, stream>>>(xb, 6144, wkb, bk, kbf, 768);
  gemm_bt<true><<<dim3(16, 6), 256, 0, stream>>>(xb, 6144, wvb, bv, vbf, 768);

  attn_kernel<<<dim3(64, 48), 256, 0, stream>>>(qbf, kbf, vbf, ctxb);

  // output projection -> f32
  gemm_bt<false><<<dim3(128, 6), 256, 0, stream>>>(ctxb, 768, wob, bo, d_out, 768);
}

// Round 2
// 281.943 us; speedup vs baseline: 1.4516x; 1.4516x over previous
//
#include <hip/hip_runtime.h>

typedef __attribute__((ext_vector_type(8))) short short8;
typedef __attribute__((ext_vector_type(4))) short short4v;
typedef __attribute__((ext_vector_type(4))) float f32x4;

#define AS1 __attribute__((address_space(1)))
#define AS3 __attribute__((address_space(3)))

__device__ __forceinline__ void gld16(const void* g, void* l) {
  __builtin_amdgcn_global_load_lds((const AS1 void*)g, (AS3 void*)l, 16, 0, 0);
}

__device__ __forceinline__ short f2bf(float f) {
  unsigned u = __builtin_bit_cast(unsigned, f);
  unsigned r = (u + 0x7fffu + ((u >> 16) & 1u)) >> 16;
  return (short)r;
}

#define MFMA(a, b, c) __builtin_amdgcn_mfma_f32_16x16x32_bf16((a), (b), (c), 0, 0, 0)

// ---------------------------------------------------------------- cast f32->bf16
__global__ void cast_f32_bf16(const float* __restrict__ in, short* __restrict__ out, int n4) {
  int i = blockIdx.x * 256 + threadIdx.x;
  if (i >= n4) return;
  f32x4 v = ((const f32x4*)in)[i];
  short4v o;
  o[0] = f2bf(v[0]); o[1] = f2bf(v[1]); o[2] = f2bf(v[2]); o[3] = f2bf(v[3]);
  ((short4v*)out)[i] = o;
}

// ---------------------------------------------------------------- GEMM: C = (A(MxK, lda) @ B(NxK,768)^T + bias) * oscale
// 128x128 tile, BK=32, 4 waves (each 64x64), global_load_lds staging.
// OUT mode: 0 = f32 row-major, 1 = bf16 row-major, 2 = bf16 transposed per-(b,h)
//   (mode 2: row = b*512+key, col = h*64+d -> out[(b*12+h)*32768 + d*512 + key])
template <int OUT>
__global__ __launch_bounds__(256) void gemm_bt(const short* __restrict__ A, int lda,
                                               const short* __restrict__ B,
                                               const float* __restrict__ bias,
                                               void* __restrict__ Cv, int K,
                                               float oscale) {
  __shared__ alignas(16) short As[128 * 32];
  __shared__ alignas(16) short Bs[128 * 32];
  const int tid = threadIdx.x, wave = tid >> 6, lane = tid & 63;
  const int bm = blockIdx.x * 128, bn = blockIdx.y * 128;
  const int wr = (wave >> 1) * 64, wc = (wave & 1) * 64;
  const int l15 = lane & 15, g = lane >> 4;
  const int srow = lane >> 2;          // row within 16-row chunk
  const int skoff = (lane & 3) * 8;    // k element offset of this lane's 16B

  f32x4 zero = {0.f, 0.f, 0.f, 0.f};
  f32x4 acc[4][4];
#pragma unroll
  for (int m = 0; m < 4; ++m)
#pragma unroll
    for (int n = 0; n < 4; ++n) acc[m][n] = zero;

  for (int kt = 0; kt < K; kt += 32) {
#pragma unroll
    for (int c = 0; c < 2; ++c) {
      int chunk = wave * 2 + c;
      int r = chunk * 16 + srow;
      gld16(A + (size_t)(bm + r) * lda + kt + skoff, (char*)As + chunk * 1024);
      gld16(B + (size_t)(bn + r) * 768 + kt + skoff, (char*)Bs + chunk * 1024);
    }
    __syncthreads();
    short8 af[4], bfr[4];
#pragma unroll
    for (int m = 0; m < 4; ++m)
      af[m] = *(const short8*)((const char*)As + (wr + 16 * m + l15) * 64 + g * 16);
#pragma unroll
    for (int n = 0; n < 4; ++n)
      bfr[n] = *(const short8*)((const char*)Bs + (wc + 16 * n + l15) * 64 + g * 16);
#pragma unroll
    for (int m = 0; m < 4; ++m)
#pragma unroll
      for (int n = 0; n < 4; ++n) acc[m][n] = MFMA(af[m], bfr[n], acc[m][n]);
    __syncthreads();
  }

#pragma unroll
  for (int m = 0; m < 4; ++m)
#pragma unroll
    for (int n = 0; n < 4; ++n) {
      int col = bn + wc + 16 * n + l15;
      float bv = bias[col];
      if (OUT == 2) {
        int row0 = bm + wr + 16 * m + g * 4;  // 4 consecutive keys
        short4v pk;
#pragma unroll
        for (int r = 0; r < 4; ++r) pk[r] = f2bf((acc[m][n][r] + bv) * oscale);
        size_t addr = (size_t)((row0 >> 9) * 12 + (col >> 6)) * 32768 +
                      (size_t)(col & 63) * 512 + (row0 & 511);
        *(short4v*)((short*)Cv + addr) = pk;
      } else {
#pragma unroll
        for (int r = 0; r < 4; ++r) {
          int row = bm + wr + 16 * m + g * 4 + r;
          float v = (acc[m][n][r] + bv) * oscale;
          if (OUT == 1)
            ((short*)Cv)[(size_t)row * 768 + col] = f2bf(v);
          else
            ((float*)Cv)[(size_t)row * 768 + col] = v;
        }
      }
    }
}

// ---------------------------------------------------------------- attention
// block = (b,h, 64 q-rows), 4 waves x 16 q-rows. 512 dilated keys.
// K staged to LDS swizzled ((key&7)<<4); V^T staged swizzled ((d&7)<<4).
// Q comes in pre-scaled by 0.125*log2e so scores are in the exp2 domain.
__global__ __launch_bounds__(256) void attn_kernel(const short* __restrict__ qb,
                                                   const short* __restrict__ kb,
                                                   const short* __restrict__ vt,
                                                   short* __restrict__ ctxb) {
  __shared__ alignas(16) char kv[32768];     // K: 256 keys x 64 bf16 | V^T: 64 d x 256 keys
  __shared__ alignas(16) char plds[4096];    // 4 waves x (16 q x 32 keys bf16)
  const int tid = threadIdx.x, wave = tid >> 6, lane = tid & 63;
  const int b = blockIdx.y / 12, h = blockIdx.y % 12;
  const int qbase = blockIdx.x * 64;
  const int l15 = lane & 15, g = lane >> 4;

  // Q fragments: 16 rows x 64 k, two K=32 steps
  const short* qrow = qb + (size_t)(b * 4096 + qbase + wave * 16 + l15) * 768 + h * 64 + g * 8;
  short8 qa0 = *(const short8*)(qrow);
  short8 qa1 = *(const short8*)(qrow + 32);

  float s_[128];  // 32 tiles x 4 rows (log2-domain scores, this lane's column)
  f32x4 zero = {0.f, 0.f, 0.f, 0.f};

  // ---- scores: two halves of 256 keys
#pragma unroll
  for (int hh = 0; hh < 2; ++hh) {
#pragma unroll
    for (int c = 0; c < 8; ++c) {
      int chunk = wave * 8 + c;
      int key = chunk * 8 + (lane >> 3);
      int sb = ((lane & 7) * 16) ^ ((key & 7) << 4);
      gld16(kb + (size_t)(b * 512 + hh * 256 + key) * 768 + h * 64 + (sb >> 1),
            kv + chunk * 1024);
    }
    __syncthreads();
#pragma unroll
    for (int t = 0; t < 16; ++t) {
      int base = (t * 16 + l15) * 128;
      int swz = (lane & 7) << 4;
      short8 k0 = *(const short8*)(kv + ((base + g * 16) ^ swz));
      short8 k1 = *(const short8*)(kv + ((base + 64 + g * 16) ^ swz));
      f32x4 a = MFMA(qa0, k0, zero);
      a = MFMA(qa1, k1, a);
#pragma unroll
      for (int r = 0; r < 4; ++r) s_[(hh * 16 + t) * 4 + r] = a[r];
    }
    __syncthreads();
  }

  // ---- softmax (exact, two-pass, exp2 domain; rows spread over 16-lane groups)
  float mrow[4] = {-1e30f, -1e30f, -1e30f, -1e30f};
#pragma unroll
  for (int t = 0; t < 32; ++t)
#pragma unroll
    for (int r = 0; r < 4; ++r) mrow[r] = fmaxf(mrow[r], s_[t * 4 + r]);
#pragma unroll
  for (int r = 0; r < 4; ++r) {
    mrow[r] = fmaxf(mrow[r], __shfl_xor(mrow[r], 1, 64));
    mrow[r] = fmaxf(mrow[r], __shfl_xor(mrow[r], 2, 64));
    mrow[r] = fmaxf(mrow[r], __shfl_xor(mrow[r], 4, 64));
    mrow[r] = fmaxf(mrow[r], __shfl_xor(mrow[r], 8, 64));
  }
  float rsum[4] = {0.f, 0.f, 0.f, 0.f};
#pragma unroll
  for (int t = 0; t < 32; ++t)
#pragma unroll
    for (int r = 0; r < 4; ++r) {
      float p = __builtin_amdgcn_exp2f(s_[t * 4 + r] - mrow[r]);
      s_[t * 4 + r] = p;
      rsum[r] += p;
    }
#pragma unroll
  for (int r = 0; r < 4; ++r) {
    rsum[r] += __shfl_xor(rsum[r], 1, 64);
    rsum[r] += __shfl_xor(rsum[r], 2, 64);
    rsum[r] += __shfl_xor(rsum[r], 4, 64);
    rsum[r] += __shfl_xor(rsum[r], 8, 64);
  }
  float rinv[4];
#pragma unroll
  for (int r = 0; r < 4; ++r) rinv[r] = 1.0f / rsum[r];

  // ---- PV: two halves of 256 keys; V^T staged as 64 d-rows x 256 keys
  f32x4 ctx[4];
#pragma unroll
  for (int n = 0; n < 4; ++n) ctx[n] = zero;
  char* pw = plds + wave * 1024;

#pragma unroll
  for (int vv = 0; vv < 2; ++vv) {
#pragma unroll
    for (int c = 0; c < 8; ++c) {
      int chunk = wave * 8 + c;          // 0..31, 1 KB each = 2 d-rows
      int d = chunk * 2 + (lane >> 5);
      int sb = ((lane & 31) * 16) ^ ((d & 7) << 4);
      gld16(vt + (size_t)((b * 12 + h) * 64 + d) * 512 + vv * 256 + (sb >> 1),
            kv + chunk * 1024);
    }
    __syncthreads();
#pragma unroll
    for (int kk = 0; kk < 8; ++kk) {
      // transpose this wave's P chunk (16 q x 32 keys) through LDS
#pragma unroll
      for (int tt = 0; tt < 2; ++tt)
#pragma unroll
        for (int r = 0; r < 4; ++r) {
          int row = g * 4 + r;
          int byte = (row * 64 + (tt * 16 + l15) * 2) ^ ((row & 7) << 4);
          *(short*)(pw + byte) = f2bf(s_[(vv * 16 + kk * 2 + tt) * 4 + r]);
        }
      short8 pa = *(const short8*)(pw + ((l15 * 64 + g * 16) ^ ((lane & 7) << 4)));
#pragma unroll
      for (int n = 0; n < 4; ++n) {
        int row = 16 * n + l15;          // d within head
        int byte = (row * 512 + kk * 64 + g * 16) ^ ((row & 7) << 4);
        short8 vf = *(const short8*)(kv + byte);
        ctx[n] = MFMA(pa, vf, ctx[n]);
      }
    }
    __syncthreads();
  }

  // ---- write ctx (bf16) in (B,S,D) layout
  size_t rowbase = (size_t)(b * 4096 + qbase + wave * 16);
#pragma unroll
  for (int n = 0; n < 4; ++n)
#pragma unroll
    for (int r = 0; r < 4; ++r) {
      int row = g * 4 + r;
      float v = ctx[n][r] * rinv[r];
      ctxb[(rowbase + row) * 768 + h * 64 + 16 * n + l15] = f2bf(v);
    }
}

// ---------------------------------------------------------------- launch
extern "C" void kernel_launch(void* const* d_in, const int* in_sizes, int n_in,
                              void* d_out, int out_size, void* d_ws, size_t ws_size,
                              hipStream_t stream) {
  const float* x  = (const float*)d_in[0];
  const float* Wq = (const float*)d_in[1];
  const float* bq = (const float*)d_in[2];
  const float* Wk = (const float*)d_in[3];
  const float* bk = (const float*)d_in[4];
  const float* Wv = (const float*)d_in[5];
  const float* bv = (const float*)d_in[6];
  const float* Wo = (const float*)d_in[7];
  const float* bo = (const float*)d_in[8];

  char* ws = (char*)d_ws;
  const size_t XB_OFF = 0;                       // 16384x768 bf16 (reused as ctx)
  const size_t WQ_OFF = 25165824;
  const size_t WK_OFF = WQ_OFF + 1179648;
  const size_t WV_OFF = WK_OFF + 1179648;
  const size_t WO_OFF = WV_OFF + 1179648;
  const size_t Q_OFF  = WO_OFF + 1179648;        // 16384x768 bf16
  const size_t K_OFF  = Q_OFF + 25165824;        // 2048x768 bf16
  const size_t V_OFF  = K_OFF + 3145728;         // V^T: (b,h) x 64d x 512key bf16

  short* xb   = (short*)(ws + XB_OFF);
  short* ctxb = xb;  // xb dead after V-projection; reuse for ctx
  short* wqb  = (short*)(ws + WQ_OFF);
  short* wkb  = (short*)(ws + WK_OFF);
  short* wvb  = (short*)(ws + WV_OFF);
  short* wob  = (short*)(ws + WO_OFF);
  short* qbf  = (short*)(ws + Q_OFF);
  short* kbf  = (short*)(ws + K_OFF);
  short* vtb  = (short*)(ws + V_OFF);

  cast_f32_bf16<<<12288, 256, 0, stream>>>(x, xb, 3145728);
  cast_f32_bf16<<<576, 256, 0, stream>>>(Wq, wqb, 147456);
  cast_f32_bf16<<<576, 256, 0, stream>>>(Wk, wkb, 147456);
  cast_f32_bf16<<<576, 256, 0, stream>>>(Wv, wvb, 147456);
  cast_f32_bf16<<<576, 256, 0, stream>>>(Wo, wob, 147456);

  const float QSCALE = 0.18033688011112042f;  // (1/sqrt(64)) * log2(e)

  // Q projection: all 16384 rows, pre-scaled into exp2 domain
  gemm_bt<1><<<dim3(128, 6), 256, 0, stream>>>(xb, 768, wqb, bq, qbf, 768, QSCALE);
  // K projection: dilated rows only (row m -> x row stride 8*768 = 6144)
  gemm_bt<1><<<dim3(16, 6), 256, 0, stream>>>(xb, 6144, wkb, bk, kbf, 768, 1.0f);
  // V projection: dilated rows, output transposed per (b,h) -> V^T[d][key]
  gemm_bt<2><<<dim3(16, 6), 256, 0, stream>>>(xb, 6144, wvb, bv, vtb, 768, 1.0f);

  attn_kernel<<<dim3(64, 48), 256, 0, stream>>>(qbf, kbf, vtb, ctxb);

  // output projection -> f32
  gemm_bt<0><<<dim3(128, 6), 256, 0, stream>>>(ctxb, 768, wob, bo, d_out, 768, 1.0f);
}

// Round 5
// 245.356 us; speedup vs baseline: 1.6681x; 1.1491x over previous
//
#include <hip/hip_runtime.h>

typedef __attribute__((ext_vector_type(8))) short short8;
typedef __attribute__((ext_vector_type(4))) short short4v;
typedef __attribute__((ext_vector_type(4))) float f32x4;

#define AS1 __attribute__((address_space(1)))
#define AS3 __attribute__((address_space(3)))

__device__ __forceinline__ void gld16(const void* g, void* l) {
  __builtin_amdgcn_global_load_lds((const AS1 void*)g, (AS3 void*)l, 16, 0, 0);
}

__device__ __forceinline__ short f2bf(float f) {
  unsigned u = __builtin_bit_cast(unsigned, f);
  unsigned r = (u + 0x7fffu + ((u >> 16) & 1u)) >> 16;
  return (short)r;
}

template <int N>
__device__ __forceinline__ void wait_vm() {
  asm volatile("s_waitcnt vmcnt(%0)" ::"i"(N) : "memory");
}
__device__ __forceinline__ void bar() { __builtin_amdgcn_s_barrier(); }

#define MFMA(a, b, c) __builtin_amdgcn_mfma_f32_16x16x32_bf16((a), (b), (c), 0, 0, 0)

// ---------------------------------------------------------------- cast f32->bf16
__global__ void cast_f32_bf16(const float* __restrict__ in, short* __restrict__ out, int n4) {
  int i = blockIdx.x * 256 + threadIdx.x;
  if (i >= n4) return;
  f32x4 v = ((const f32x4*)in)[i];
  short4v o;
  o[0] = f2bf(v[0]); o[1] = f2bf(v[1]); o[2] = f2bf(v[2]); o[3] = f2bf(v[3]);
  ((short4v*)out)[i] = o;
}

// merged cast of the four 768x768 weights (dst regions contiguous)
__global__ void cast4_f32_bf16(const float* __restrict__ s0, const float* __restrict__ s1,
                               const float* __restrict__ s2, const float* __restrict__ s3,
                               short* __restrict__ out) {
  const float* src = (blockIdx.y == 0) ? s0 : (blockIdx.y == 1) ? s1 : (blockIdx.y == 2) ? s2 : s3;
  int i = blockIdx.x * 256 + threadIdx.x;  // < 147456
  f32x4 v = ((const f32x4*)src)[i];
  short4v o;
  o[0] = f2bf(v[0]); o[1] = f2bf(v[1]); o[2] = f2bf(v[2]); o[3] = f2bf(v[3]);
  ((short4v*)(out + (size_t)blockIdx.y * 589824))[i] = o;
}

// ---------------------------------------------------------------- GEMM: C = (A(MxK,lda) @ B(NxK,768)^T + bias) * oscale
// OUT: 0 = f32 row-major, 1 = bf16 row-major,
//      3 = merged K|V: col<768 -> bf16 row-major (K); col>=768 -> V^T per (b,h)
//          with key-permutation pi (slot bits: s4s3=k3k2, s2=k4, s1s0=k1k0)
template <int OUT>
__global__ __launch_bounds__(256) void gemm_bt(const short* __restrict__ A, int lda,
                                               const short* __restrict__ B,
                                               const float* __restrict__ bias,
                                               const float* __restrict__ bias2,
                                               void* __restrict__ Cv, void* __restrict__ Cv2,
                                               int K, float oscale) {
  __shared__ alignas(16) short As[128 * 32];
  __shared__ alignas(16) short Bs[128 * 32];
  const int tid = threadIdx.x, wave = tid >> 6, lane = tid & 63;
  const int bm = blockIdx.x * 128, bn = blockIdx.y * 128;
  const int wr = (wave >> 1) * 64, wc = (wave & 1) * 64;
  const int l15 = lane & 15, g = lane >> 4;
  const int srow = lane >> 2;
  const int skoff = (lane & 3) * 8;

  f32x4 zero = {0.f, 0.f, 0.f, 0.f};
  f32x4 acc[4][4];
#pragma unroll
  for (int m = 0; m < 4; ++m)
#pragma unroll
    for (int n = 0; n < 4; ++n) acc[m][n] = zero;

  for (int kt = 0; kt < K; kt += 32) {
#pragma unroll
    for (int c = 0; c < 2; ++c) {
      int chunk = wave * 2 + c;
      int r = chunk * 16 + srow;
      gld16(A + (size_t)(bm + r) * lda + kt + skoff, (char*)As + chunk * 1024);
      gld16(B + (size_t)(bn + r) * 768 + kt + skoff, (char*)Bs + chunk * 1024);
    }
    __syncthreads();
    short8 af[4], bfr[4];
#pragma unroll
    for (int m = 0; m < 4; ++m)
      af[m] = *(const short8*)((const char*)As + (wr + 16 * m + l15) * 64 + g * 16);
#pragma unroll
    for (int n = 0; n < 4; ++n)
      bfr[n] = *(const short8*)((const char*)Bs + (wc + 16 * n + l15) * 64 + g * 16);
#pragma unroll
    for (int m = 0; m < 4; ++m)
#pragma unroll
      for (int n = 0; n < 4; ++n) acc[m][n] = MFMA(af[m], bfr[n], acc[m][n]);
    __syncthreads();
  }

#pragma unroll
  for (int m = 0; m < 4; ++m)
#pragma unroll
    for (int n = 0; n < 4; ++n) {
      int col = bn + wc + 16 * n + l15;
      if (OUT == 3 && col >= 768) {
        // V path: transposed + key-permuted store
        float bv = bias2[col - 768];
        int hh = col - 768;
        int h = hh >> 6, d = hh & 63;
        int row0 = bm + wr + 16 * m + g * 4;          // 4 consecutive keys
        int bb = row0 >> 9, kloc = row0 & 511;
        int slot = ((kloc >> 5) << 5) + (((kloc >> 2) & 3) << 3) + (((kloc >> 4) & 1) << 2);
        short4v pk;
#pragma unroll
        for (int r = 0; r < 4; ++r) pk[r] = f2bf((acc[m][n][r] + bv) * oscale);
        *(short4v*)((short*)Cv2 + (size_t)((bb * 12 + h) * 64 + d) * 512 + slot) = pk;
      } else {
        float bv = bias[col];
#pragma unroll
        for (int r = 0; r < 4; ++r) {
          int row = bm + wr + 16 * m + g * 4 + r;
          float v = (acc[m][n][r] + bv) * oscale;
          if (OUT == 0)
            ((float*)Cv)[(size_t)row * 768 + col] = v;
          else
            ((short*)Cv)[(size_t)row * 768 + col] = f2bf(v);
        }
      }
    }
}

// ---------------------------------------------------------------- attention
// block = (b,h, 64 q-rows), 4 waves x 16 q-rows. 512 keys, 4 chunks of 128
// ping-ponged through two 16KB LDS buffers with counted vmcnt.
// Swapped QK^T (S^T in regs, lane l15 = q-row); all 128 scores/lane kept in
// f32 regs; EXACT global-max two-pass softmax (round-2 numerics: dominant
// P = exp2(0) = 1.0 exact in bf16, no rescales). V^T key-permuted so P
// A-frags are lane-local.
__global__ __launch_bounds__(256, 2) void attn_kernel(const short* __restrict__ qb,
                                                      const short* __restrict__ kb,
                                                      const short* __restrict__ vt,
                                                      short* __restrict__ ctxb) {
  __shared__ alignas(16) char lds[32768];
  char* bufA = lds;
  char* bufB = lds + 16384;
  const int tid = threadIdx.x, wave = tid >> 6, lane = tid & 63;
  const int b = blockIdx.y / 12, h = blockIdx.y % 12;
  const int qbase = blockIdx.x * 64;
  const int l15 = lane & 15, g = lane >> 4, g4 = g * 4;

  // Q fragments (B-operand): lane l15 = q-row
  const short* qrow = qb + (size_t)(b * 4096 + qbase + wave * 16 + l15) * 768 + h * 64 + g * 8;
  short8 qa0 = *(const short8*)(qrow);
  short8 qa1 = *(const short8*)(qrow + 32);

  f32x4 zero = {0.f, 0.f, 0.f, 0.f};
  f32x4 st[32];  // all 512 keys: st[ci*8 + t][r] = S[key = ci*128 + t*16 + g*4 + r][q = l15]

  const int krow_g = (lane & 7) * 16;        // K staging: byte within row, pre-swizzle
  const int kkey = wave * 32 + (lane >> 3);  // +c*8
  const int vd = wave * 16 + (lane >> 4);    // +c*4
  const int vcol = (lane & 15) * 16;
  const size_t kgbase = (size_t)(b * 512) * 768 + h * 64;
  const size_t vgbase = (size_t)((b * 12 + h) * 64) * 512;
  const int kswz = (l15 & 7) << 4;

#define STAGE_K(ci, dst)                                                              \
  _Pragma("unroll") for (int c = 0; c < 4; ++c) {                                     \
    int key = kkey + c * 8;                                                           \
    int sb = krow_g ^ ((key & 7) << 4);                                               \
    gld16(kb + kgbase + (size_t)((ci)*128 + key) * 768 + (sb >> 1),                   \
          (dst) + (wave * 32 + c * 8) * 128);                                         \
  }
#define STAGE_V(ci, dst)                                                              \
  _Pragma("unroll") for (int c = 0; c < 4; ++c) {                                     \
    int d = vd + c * 4;                                                               \
    int sb = vcol ^ ((d & 7) << 4);                                                   \
    gld16(vt + vgbase + (size_t)d * 512 + (ci)*128 + (sb >> 1),                       \
          (dst) + (wave * 16 + c * 4) * 256);                                         \
  }
#define QK_CHUNK(ci, buf)                                                             \
  __builtin_amdgcn_s_setprio(1);                                                      \
  _Pragma("unroll") for (int t = 0; t < 8; ++t) {                                     \
    int base = (t * 16 + l15) * 128;                                                  \
    short8 k0 = *(const short8*)((buf) + (base + ((g * 16) ^ kswz)));                 \
    short8 k1 = *(const short8*)((buf) + (base + ((g * 16 + 64) ^ kswz)));            \
    f32x4 a = MFMA(k0, qa0, zero);                                                    \
    st[(ci)*8 + t] = MFMA(k1, qa1, a);                                                \
  }                                                                                   \
  __builtin_amdgcn_s_setprio(0);
#define PV_CHUNK(ci, buf)                                                             \
  __builtin_amdgcn_s_setprio(1);                                                      \
  _Pragma("unroll") for (int kk = 0; kk < 4; ++kk) {                                  \
    f32x4 s0 = st[(ci)*8 + 2 * kk], s1 = st[(ci)*8 + 2 * kk + 1];                     \
    short8 pa;                                                                        \
    pa[0] = f2bf(s0[0]); pa[1] = f2bf(s0[1]); pa[2] = f2bf(s0[2]); pa[3] = f2bf(s0[3]);\
    pa[4] = f2bf(s1[0]); pa[5] = f2bf(s1[1]); pa[6] = f2bf(s1[2]); pa[7] = f2bf(s1[3]);\
    _Pragma("unroll") for (int n = 0; n < 4; ++n) {                                   \
      int row = 16 * n + l15;                                                         \
      short8 vf = *(const short8*)((buf) + row * 256 + ((kk * 64 + g * 16) ^ ((row & 7) << 4))); \
      ctx[n] = MFMA(pa, vf, ctx[n]);                                                  \
    }                                                                                 \
  }                                                                                   \
  __builtin_amdgcn_s_setprio(0);

  // ---------------- phase 1: QK^T over 4 chunks, K ping-pong A/B
  STAGE_K(0, bufA);
  STAGE_K(1, bufB);

  wait_vm<4>(); bar();
  QK_CHUNK(0, bufA);
  bar(); asm volatile("" ::: "memory");
  STAGE_K(2, bufA);

  wait_vm<4>(); bar();
  QK_CHUNK(1, bufB);
  bar(); asm volatile("" ::: "memory");
  STAGE_K(3, bufB);

  wait_vm<4>(); bar();
  QK_CHUNK(2, bufA);
  bar(); asm volatile("" ::: "memory");
  STAGE_V(0, bufA);

  wait_vm<4>(); bar();
  QK_CHUNK(3, bufB);
  bar(); asm volatile("" ::: "memory");
  STAGE_V(1, bufB);

  // ---------------- phase 2: exact global softmax (exp2 domain), q = l15
  float m = st[0][0];
#pragma unroll
  for (int t = 0; t < 32; ++t)
#pragma unroll
    for (int r = 0; r < 4; ++r) m = fmaxf(m, st[t][r]);
  m = fmaxf(m, __shfl_xor(m, 16, 64));
  m = fmaxf(m, __shfl_xor(m, 32, 64));
  float l = 0.f;
#pragma unroll
  for (int t = 0; t < 32; ++t)
#pragma unroll
    for (int r = 0; r < 4; ++r) {
      float p = __builtin_amdgcn_exp2f(st[t][r] - m);
      st[t][r] = p;
      l += p;
    }
  l += __shfl_xor(l, 16, 64);
  l += __shfl_xor(l, 32, 64);

  // ---------------- phase 3: PV over 4 chunks, V ping-pong A/B
  f32x4 ctx[4];
#pragma unroll
  for (int n = 0; n < 4; ++n) ctx[n] = zero;

  wait_vm<4>(); bar();
  PV_CHUNK(0, bufA);
  bar(); asm volatile("" ::: "memory");
  STAGE_V(2, bufA);

  wait_vm<4>(); bar();
  PV_CHUNK(1, bufB);
  bar(); asm volatile("" ::: "memory");
  STAGE_V(3, bufB);

  wait_vm<4>(); bar();
  PV_CHUNK(2, bufA);

  wait_vm<0>(); bar();
  PV_CHUNK(3, bufB);

  // ---------------- epilogue: normalize (rinv held at q=l15 -> q=g*4+r)
  float rinv = 1.0f / l;
  float rw0 = __shfl(rinv, g4, 64), rw1 = __shfl(rinv, g4 + 1, 64);
  float rw2 = __shfl(rinv, g4 + 2, 64), rw3 = __shfl(rinv, g4 + 3, 64);
  size_t rowbase = (size_t)(b * 4096 + qbase + wave * 16);
#pragma unroll
  for (int n = 0; n < 4; ++n) {
    int col = h * 64 + 16 * n + l15;
    ctxb[(rowbase + g4 + 0) * 768 + col] = f2bf(ctx[n][0] * rw0);
    ctxb[(rowbase + g4 + 1) * 768 + col] = f2bf(ctx[n][1] * rw1);
    ctxb[(rowbase + g4 + 2) * 768 + col] = f2bf(ctx[n][2] * rw2);
    ctxb[(rowbase + g4 + 3) * 768 + col] = f2bf(ctx[n][3] * rw3);
  }
#undef STAGE_K
#undef STAGE_V
#undef QK_CHUNK
#undef PV_CHUNK
}

// ---------------------------------------------------------------- launch
extern "C" void kernel_launch(void* const* d_in, const int* in_sizes, int n_in,
                              void* d_out, int out_size, void* d_ws, size_t ws_size,
                              hipStream_t stream) {
  const float* x  = (const float*)d_in[0];
  const float* Wq = (const float*)d_in[1];
  const float* bq = (const float*)d_in[2];
  const float* Wk = (const float*)d_in[3];
  const float* bk = (const float*)d_in[4];
  const float* Wv = (const float*)d_in[5];
  const float* bv = (const float*)d_in[6];
  const float* Wo = (const float*)d_in[7];
  const float* bo = (const float*)d_in[8];

  char* ws = (char*)d_ws;
  const size_t XB_OFF = 0;                       // 16384x768 bf16 (reused as ctx)
  const size_t WQ_OFF = 25165824;
  const size_t WK_OFF = WQ_OFF + 1179648;
  const size_t WV_OFF = WK_OFF + 1179648;        // contiguous after WK (merged B)
  const size_t WO_OFF = WV_OFF + 1179648;
  const size_t Q_OFF  = WO_OFF + 1179648;        // 16384x768 bf16
  const size_t K_OFF  = Q_OFF + 25165824;        // 2048x768 bf16
  const size_t V_OFF  = K_OFF + 3145728;         // V^T: (b,h) x 64d x 512slot bf16

  short* xb   = (short*)(ws + XB_OFF);
  short* ctxb = xb;  // xb dead after projections; reuse for ctx
  short* wqb  = (short*)(ws + WQ_OFF);
  short* wkb  = (short*)(ws + WK_OFF);
  short* wob  = (short*)(ws + WO_OFF);
  short* qbf  = (short*)(ws + Q_OFF);
  short* kbf  = (short*)(ws + K_OFF);
  short* vtb  = (short*)(ws + V_OFF);

  cast_f32_bf16<<<12288, 256, 0, stream>>>(x, xb, 3145728);
  cast4_f32_bf16<<<dim3(576, 4), 256, 0, stream>>>(Wq, Wk, Wv, Wo, wqb);

  const float QSCALE = 0.18033688011112042f;  // (1/sqrt(64)) * log2(e)

  // Q projection: all 16384 rows, pre-scaled into exp2 domain
  gemm_bt<1><<<dim3(128, 6), 256, 0, stream>>>(xb, 768, wqb, bq, nullptr, qbf, nullptr, 768, QSCALE);
  // merged K|V projection: dilated rows (lda = 8*768), cols 0..767 = K, 768..1535 = V
  gemm_bt<3><<<dim3(16, 12), 256, 0, stream>>>(xb, 6144, wkb, bk, bv, kbf, vtb, 768, 1.0f);

  attn_kernel<<<dim3(64, 48), 256, 0, stream>>>(qbf, kbf, vtb, ctxb);

  // output projection -> f32
  gemm_bt<0><<<dim3(128, 6), 256, 0, stream>>>(ctxb, 768, wob, bo, nullptr, d_out, nullptr, 768, 1.0f);
}

// Round 6
// 236.914 us; speedup vs baseline: 1.7275x; 1.0356x over previous
//
#include <hip/hip_runtime.h>

typedef __attribute__((ext_vector_type(8))) short short8;
typedef __attribute__((ext_vector_type(4))) short short4v;
typedef __attribute__((ext_vector_type(4))) float f32x4;
typedef __attribute__((ext_vector_type(4))) unsigned uint32x4;

#define AS1 __attribute__((address_space(1)))
#define AS3 __attribute__((address_space(3)))

__device__ __forceinline__ void gld16(const void* g, void* l) {
  __builtin_amdgcn_global_load_lds((const AS1 void*)g, (AS3 void*)l, 16, 0, 0);
}

__device__ __forceinline__ short f2bf(float f) {
  unsigned u = __builtin_bit_cast(unsigned, f);
  unsigned r = (u + 0x7fffu + ((u >> 16) & 1u)) >> 16;
  return (short)r;
}

template <int N>
__device__ __forceinline__ void wait_vm() {
  asm volatile("s_waitcnt vmcnt(%0)" ::"i"(N) : "memory");
}
__device__ __forceinline__ void bar() { __builtin_amdgcn_s_barrier(); }

#define MFMA(a, b, c) __builtin_amdgcn_mfma_f32_16x16x32_bf16((a), (b), (c), 0, 0, 0)

// ---------------------------------------------------------------- cast f32->bf16
__global__ void cast_f32_bf16(const float* __restrict__ in, short* __restrict__ out, int n4) {
  int i = blockIdx.x * 256 + threadIdx.x;
  if (i >= n4) return;
  f32x4 v = ((const f32x4*)in)[i];
  short4v o;
  o[0] = f2bf(v[0]); o[1] = f2bf(v[1]); o[2] = f2bf(v[2]); o[3] = f2bf(v[3]);
  ((short4v*)out)[i] = o;
}

// merged cast of the four 768x768 weights (dst regions contiguous)
__global__ void cast4_f32_bf16(const float* __restrict__ s0, const float* __restrict__ s1,
                               const float* __restrict__ s2, const float* __restrict__ s3,
                               short* __restrict__ out) {
  const float* src = (blockIdx.y == 0) ? s0 : (blockIdx.y == 1) ? s1 : (blockIdx.y == 2) ? s2 : s3;
  int i = blockIdx.x * 256 + threadIdx.x;  // < 147456
  f32x4 v = ((const f32x4*)src)[i];
  short4v o;
  o[0] = f2bf(v[0]); o[1] = f2bf(v[1]); o[2] = f2bf(v[2]); o[3] = f2bf(v[3]);
  ((short4v*)(out + (size_t)blockIdx.y * 589824))[i] = o;
}

// ---------------------------------------------------------------- GEMM: C = (A(MxK,lda) @ B(NxK,768)^T + bias) * oscale
// 128x128 tile, BK=64 (24 barriers for K=768), 4 waves, global_load_lds staging
// with XOR-swizzled rows ((row&7)<<4 involution, pre-swizzled global source)
// -> conflict-free ds_read_b128.
// OUT: 0 = f32 row-major, 1 = bf16 row-major,
//      3 = merged K|V: col<768 -> bf16 row-major (K); col>=768 -> V^T per (b,h)
//          with key-permutation pi (slot bits: s4s3=k3k2, s2=k4, s1s0=k1k0)
template <int OUT>
__global__ __launch_bounds__(256) void gemm_bt(const short* __restrict__ A, int lda,
                                               const short* __restrict__ B,
                                               const float* __restrict__ bias,
                                               const float* __restrict__ bias2,
                                               void* __restrict__ Cv, void* __restrict__ Cv2,
                                               int K, float oscale) {
  __shared__ alignas(16) short As[128 * 64];
  __shared__ alignas(16) short Bs[128 * 64];
  const int tid = threadIdx.x, wave = tid >> 6, lane = tid & 63;
  const int bm = blockIdx.x * 128, bn = blockIdx.y * 128;
  const int wr = (wave >> 1) * 64, wc = (wave & 1) * 64;
  const int l15 = lane & 15, g = lane >> 4;
  const int srow = lane >> 3;                        // row within 8-row chunk
  const int sb = ((lane & 7) * 16) ^ (srow << 4);    // pre-swizzled byte within 128B row
  const int rswz = (l15 & 7) << 4;

  f32x4 zero = {0.f, 0.f, 0.f, 0.f};
  f32x4 acc[4][4];
#pragma unroll
  for (int m = 0; m < 4; ++m)
#pragma unroll
    for (int n = 0; n < 4; ++n) acc[m][n] = zero;

  for (int kt = 0; kt < K; kt += 64) {
#pragma unroll
    for (int c = 0; c < 4; ++c) {
      int chunk = wave * 4 + c;
      int r = chunk * 8 + srow;
      gld16(A + (size_t)(bm + r) * lda + kt + (sb >> 1), (char*)As + chunk * 1024);
      gld16(B + (size_t)(bn + r) * 768 + kt + (sb >> 1), (char*)Bs + chunk * 1024);
    }
    __syncthreads();
#pragma unroll
    for (int kk = 0; kk < 2; ++kk) {
      short8 af[4], bfr[4];
#pragma unroll
      for (int m = 0; m < 4; ++m)
        af[m] = *(const short8*)((const char*)As + (wr + 16 * m + l15) * 128 +
                                 ((kk * 64 + g * 16) ^ rswz));
#pragma unroll
      for (int n = 0; n < 4; ++n)
        bfr[n] = *(const short8*)((const char*)Bs + (wc + 16 * n + l15) * 128 +
                                  ((kk * 64 + g * 16) ^ rswz));
#pragma unroll
      for (int m = 0; m < 4; ++m)
#pragma unroll
        for (int n = 0; n < 4; ++n) acc[m][n] = MFMA(af[m], bfr[n], acc[m][n]);
    }
    __syncthreads();
  }

#pragma unroll
  for (int m = 0; m < 4; ++m)
#pragma unroll
    for (int n = 0; n < 4; ++n) {
      int col = bn + wc + 16 * n + l15;
      if (OUT == 3 && col >= 768) {
        // V path: transposed + key-permuted store
        float bv = bias2[col - 768];
        int hh = col - 768;
        int h = hh >> 6, d = hh & 63;
        int row0 = bm + wr + 16 * m + g * 4;          // 4 consecutive keys
        int bb = row0 >> 9, kloc = row0 & 511;
        int slot = ((kloc >> 5) << 5) + (((kloc >> 2) & 3) << 3) + (((kloc >> 4) & 1) << 2);
        short4v pk;
#pragma unroll
        for (int r = 0; r < 4; ++r) pk[r] = f2bf((acc[m][n][r] + bv) * oscale);
        *(short4v*)((short*)Cv2 + (size_t)((bb * 12 + h) * 64 + d) * 512 + slot) = pk;
      } else {
        float bv = bias[col];
#pragma unroll
        for (int r = 0; r < 4; ++r) {
          int row = bm + wr + 16 * m + g * 4 + r;
          float v = (acc[m][n][r] + bv) * oscale;
          if (OUT == 0)
            ((float*)Cv)[(size_t)row * 768 + col] = v;
          else
            ((short*)Cv)[(size_t)row * 768 + col] = f2bf(v);
        }
      }
    }
}

// ---------------------------------------------------------------- attention
// block = (b,h, 64 q-rows), 4 waves x 16 q-rows. 512 keys, 4 chunks of 128
// ping-ponged through two 16KB LDS buffers with counted vmcnt.
// Swapped QK^T (S^T in regs, lane l15 = q-row); all 128 scores/lane kept in
// f32 regs; EXACT global-max two-pass softmax (dominant P = 1.0 exact in
// bf16, no rescales). V^T key-permuted so P A-frags are lane-local; P packed
// to bf16 via v_cvt_pk_bf16_f32 (2 values/op).
__global__ __launch_bounds__(256, 2) void attn_kernel(const short* __restrict__ qb,
                                                      const short* __restrict__ kb,
                                                      const short* __restrict__ vt,
                                                      short* __restrict__ ctxb) {
  __shared__ alignas(16) char lds[32768];
  char* bufA = lds;
  char* bufB = lds + 16384;
  const int tid = threadIdx.x, wave = tid >> 6, lane = tid & 63;
  const int b = blockIdx.y / 12, h = blockIdx.y % 12;
  const int qbase = blockIdx.x * 64;
  const int l15 = lane & 15, g = lane >> 4, g4 = g * 4;

  // Q fragments (B-operand): lane l15 = q-row
  const short* qrow = qb + (size_t)(b * 4096 + qbase + wave * 16 + l15) * 768 + h * 64 + g * 8;
  short8 qa0 = *(const short8*)(qrow);
  short8 qa1 = *(const short8*)(qrow + 32);

  f32x4 zero = {0.f, 0.f, 0.f, 0.f};
  f32x4 st[32];  // all 512 keys: st[ci*8 + t][r] = S[key = ci*128 + t*16 + g*4 + r][q = l15]

  const int krow_g = (lane & 7) * 16;        // K staging: byte within row, pre-swizzle
  const int kkey = wave * 32 + (lane >> 3);  // +c*8
  const int vd = wave * 16 + (lane >> 4);    // +c*4
  const int vcol = (lane & 15) * 16;
  const size_t kgbase = (size_t)(b * 512) * 768 + h * 64;
  const size_t vgbase = (size_t)((b * 12 + h) * 64) * 512;
  const int kswz = (l15 & 7) << 4;

#define STAGE_K(ci, dst)                                                              \
  _Pragma("unroll") for (int c = 0; c < 4; ++c) {                                     \
    int key = kkey + c * 8;                                                           \
    int sb = krow_g ^ ((key & 7) << 4);                                               \
    gld16(kb + kgbase + (size_t)((ci)*128 + key) * 768 + (sb >> 1),                   \
          (dst) + (wave * 32 + c * 8) * 128);                                         \
  }
#define STAGE_V(ci, dst)                                                              \
  _Pragma("unroll") for (int c = 0; c < 4; ++c) {                                     \
    int d = vd + c * 4;                                                               \
    int sb = vcol ^ ((d & 7) << 4);                                                   \
    gld16(vt + vgbase + (size_t)d * 512 + (ci)*128 + (sb >> 1),                       \
          (dst) + (wave * 16 + c * 4) * 256);                                         \
  }
#define QK_CHUNK(ci, buf)                                                             \
  __builtin_amdgcn_s_setprio(1);                                                      \
  _Pragma("unroll") for (int t = 0; t < 8; ++t) {                                     \
    int base = (t * 16 + l15) * 128;                                                  \
    short8 k0 = *(const short8*)((buf) + (base + ((g * 16) ^ kswz)));                 \
    short8 k1 = *(const short8*)((buf) + (base + ((g * 16 + 64) ^ kswz)));            \
    f32x4 a = MFMA(k0, qa0, zero);                                                    \
    st[(ci)*8 + t] = MFMA(k1, qa1, a);                                                \
  }                                                                                   \
  __builtin_amdgcn_s_setprio(0);
#define PV_CHUNK(ci, buf)                                                             \
  __builtin_amdgcn_s_setprio(1);                                                      \
  _Pragma("unroll") for (int kk = 0; kk < 4; ++kk) {                                  \
    f32x4 s0 = st[(ci)*8 + 2 * kk], s1 = st[(ci)*8 + 2 * kk + 1];                     \
    uint32x4 u;                                                                       \
    asm("v_cvt_pk_bf16_f32 %0, %1, %2" : "=v"(u[0]) : "v"(s0[0]), "v"(s0[1]));        \
    asm("v_cvt_pk_bf16_f32 %0, %1, %2" : "=v"(u[1]) : "v"(s0[2]), "v"(s0[3]));        \
    asm("v_cvt_pk_bf16_f32 %0, %1, %2" : "=v"(u[2]) : "v"(s1[0]), "v"(s1[1]));        \
    asm("v_cvt_pk_bf16_f32 %0, %1, %2" : "=v"(u[3]) : "v"(s1[2]), "v"(s1[3]));        \
    short8 pa = __builtin_bit_cast(short8, u);                                        \
    _Pragma("unroll") for (int n = 0; n < 4; ++n) {                                   \
      int row = 16 * n + l15;                                                         \
      short8 vf = *(const short8*)((buf) + row * 256 + ((kk * 64 + g * 16) ^ ((row & 7) << 4))); \
      ctx[n] = MFMA(pa, vf, ctx[n]);                                                  \
    }                                                                                 \
  }                                                                                   \
  __builtin_amdgcn_s_setprio(0);

  // ---------------- phase 1: QK^T over 4 chunks, K ping-pong A/B
  STAGE_K(0, bufA);
  STAGE_K(1, bufB);

  wait_vm<4>(); bar();
  QK_CHUNK(0, bufA);
  bar(); asm volatile("" ::: "memory");
  STAGE_K(2, bufA);

  wait_vm<4>(); bar();
  QK_CHUNK(1, bufB);
  bar(); asm volatile("" ::: "memory");
  STAGE_K(3, bufB);

  wait_vm<4>(); bar();
  QK_CHUNK(2, bufA);
  bar(); asm volatile("" ::: "memory");
  STAGE_V(0, bufA);

  wait_vm<4>(); bar();
  QK_CHUNK(3, bufB);
  bar(); asm volatile("" ::: "memory");
  STAGE_V(1, bufB);

  // ---------------- phase 2: exact global softmax (exp2 domain), q = l15
  float m = st[0][0];
#pragma unroll
  for (int t = 0; t < 32; ++t)
#pragma unroll
    for (int r = 0; r < 4; ++r) m = fmaxf(m, st[t][r]);
  m = fmaxf(m, __shfl_xor(m, 16, 64));
  m = fmaxf(m, __shfl_xor(m, 32, 64));
  float l = 0.f;
#pragma unroll
  for (int t = 0; t < 32; ++t)
#pragma unroll
    for (int r = 0; r < 4; ++r) {
      float p = __builtin_amdgcn_exp2f(st[t][r] - m);
      st[t][r] = p;
      l += p;
    }
  l += __shfl_xor(l, 16, 64);
  l += __shfl_xor(l, 32, 64);

  // ---------------- phase 3: PV over 4 chunks, V ping-pong A/B
  f32x4 ctx[4];
#pragma unroll
  for (int n = 0; n < 4; ++n) ctx[n] = zero;

  wait_vm<4>(); bar();
  PV_CHUNK(0, bufA);
  bar(); asm volatile("" ::: "memory");
  STAGE_V(2, bufA);

  wait_vm<4>(); bar();
  PV_CHUNK(1, bufB);
  bar(); asm volatile("" ::: "memory");
  STAGE_V(3, bufB);

  wait_vm<4>(); bar();
  PV_CHUNK(2, bufA);

  wait_vm<0>(); bar();
  PV_CHUNK(3, bufB);

  // ---------------- epilogue: normalize (rinv held at q=l15 -> q=g*4+r)
  float rinv = 1.0f / l;
  float rw0 = __shfl(rinv, g4, 64), rw1 = __shfl(rinv, g4 + 1, 64);
  float rw2 = __shfl(rinv, g4 + 2, 64), rw3 = __shfl(rinv, g4 + 3, 64);
  size_t rowbase = (size_t)(b * 4096 + qbase + wave * 16);
#pragma unroll
  for (int n = 0; n < 4; ++n) {
    int col = h * 64 + 16 * n + l15;
    ctxb[(rowbase + g4 + 0) * 768 + col] = f2bf(ctx[n][0] * rw0);
    ctxb[(rowbase + g4 + 1) * 768 + col] = f2bf(ctx[n][1] * rw1);
    ctxb[(rowbase + g4 + 2) * 768 + col] = f2bf(ctx[n][2] * rw2);
    ctxb[(rowbase + g4 + 3) * 768 + col] = f2bf(ctx[n][3] * rw3);
  }
#undef STAGE_K
#undef STAGE_V
#undef QK_CHUNK
#undef PV_CHUNK
}

// ---------------------------------------------------------------- launch
extern "C" void kernel_launch(void* const* d_in, const int* in_sizes, int n_in,
                              void* d_out, int out_size, void* d_ws, size_t ws_size,
                              hipStream_t stream) {
  const float* x  = (const float*)d_in[0];
  const float* Wq = (const float*)d_in[1];
  const float* bq = (const float*)d_in[2];
  const float* Wk = (const float*)d_in[3];
  const float* bk = (const float*)d_in[4];
  const float* Wv = (const float*)d_in[5];
  const float* bv = (const float*)d_in[6];
  const float* Wo = (const float*)d_in[7];
  const float* bo = (const float*)d_in[8];

  char* ws = (char*)d_ws;
  const size_t XB_OFF = 0;                       // 16384x768 bf16 (reused as ctx)
  const size_t WQ_OFF = 25165824;
  const size_t WK_OFF = WQ_OFF + 1179648;
  const size_t WV_OFF = WK_OFF + 1179648;        // contiguous after WK (merged B)
  const size_t WO_OFF = WV_OFF + 1179648;
  const size_t Q_OFF  = WO_OFF + 1179648;        // 16384x768 bf16
  const size_t K_OFF  = Q_OFF + 25165824;        // 2048x768 bf16
  const size_t V_OFF  = K_OFF + 3145728;         // V^T: (b,h) x 64d x 512slot bf16

  short* xb   = (short*)(ws + XB_OFF);
  short* ctxb = xb;  // xb dead after projections; reuse for ctx
  short* wqb  = (short*)(ws + WQ_OFF);
  short* wkb  = (short*)(ws + WK_OFF);
  short* wob  = (short*)(ws + WO_OFF);
  short* qbf  = (short*)(ws + Q_OFF);
  short* kbf  = (short*)(ws + K_OFF);
  short* vtb  = (short*)(ws + V_OFF);

  cast_f32_bf16<<<12288, 256, 0, stream>>>(x, xb, 3145728);
  cast4_f32_bf16<<<dim3(576, 4), 256, 0, stream>>>(Wq, Wk, Wv, Wo, wqb);

  const float QSCALE = 0.18033688011112042f;  // (1/sqrt(64)) * log2(e)

  // Q projection: all 16384 rows, pre-scaled into exp2 domain
  gemm_bt<1><<<dim3(128, 6), 256, 0, stream>>>(xb, 768, wqb, bq, nullptr, qbf, nullptr, 768, QSCALE);
  // merged K|V projection: dilated rows (lda = 8*768), cols 0..767 = K, 768..1535 = V
  gemm_bt<3><<<dim3(16, 12), 256, 0, stream>>>(xb, 6144, wkb, bk, bv, kbf, vtb, 768, 1.0f);

  attn_kernel<<<dim3(64, 48), 256, 0, stream>>>(qbf, kbf, vtb, ctxb);

  // output projection -> f32
  gemm_bt<0><<<dim3(128, 6), 256, 0, stream>>>(ctxb, 768, wob, bo, nullptr, d_out, nullptr, 768, 1.0f);
}